// Round 8
// baseline (371.380 us; speedup 1.0000x reference)
//
#include <hip/hip_runtime.h>

#define N_TOK 8192
#define DIM   512
#define NREL  20
#define NGRP  40          // 2R segments (0..19 fwd, 20..39 rev)
#define OUTD  256
#define STILE 64          // self m-tiles: 8192/128
#define MAXT  168         // max padded edge m-tiles (2 * (64+20) worst case)
#define MAXP  (MAXT*128)

typedef unsigned short u16;
typedef u16    u16x8  __attribute__((ext_vector_type(8)));
typedef __bf16 bf16x8 __attribute__((ext_vector_type(8)));
typedef float  f32x4  __attribute__((ext_vector_type(4)));

__device__ __forceinline__ u16 f2bf(float f) {
  union { float f; unsigned u; } v; v.f = f;
  return (u16)((v.u + 0x7FFFu + ((v.u >> 16) & 1u)) >> 16);  // RNE
}

// ---- one dispatch converts all four fp32->bf16 buffers ----
__global__ void k_cvt4(const float* __restrict__ s0, u16* __restrict__ d0, int m0,
                       const float* __restrict__ s1, u16* __restrict__ d1, int m1,
                       const float* __restrict__ s2, u16* __restrict__ d2, int m2,
                       const float* __restrict__ s3, u16* __restrict__ d3, int m3) {
  const int stride = gridDim.x * blockDim.x;
  const int t0 = blockIdx.x * blockDim.x + threadIdx.x;
#define CVT_LOOP(S, D, N)                                                    \
  for (int i = t0; i < N; i += stride) {                                     \
    float4 v = reinterpret_cast<const float4*>(S)[i];                        \
    reinterpret_cast<ushort4*>(D)[i] =                                       \
        make_ushort4(f2bf(v.x), f2bf(v.y), f2bf(v.z), f2bf(v.w));            \
  }
  CVT_LOOP(s0, d0, m0) CVT_LOOP(s1, d1, m1) CVT_LOOP(s2, d2, m2) CVT_LOOP(s3, d3, m3)
#undef CVT_LOOP
}

// fp32 -> bf16 with ReLU (layer output)
__global__ void k_cvtr(const float* __restrict__ in, u16* __restrict__ out, int n4) {
  const int stride = gridDim.x * blockDim.x;
  for (int i = blockIdx.x * blockDim.x + threadIdx.x; i < n4; i += stride) {
    float4 v = reinterpret_cast<const float4*>(in)[i];
    reinterpret_cast<ushort4*>(out)[i] =
        make_ushort4(f2bf(fmaxf(v.x, 0.f)), f2bf(fmaxf(v.y, 0.f)),
                     f2bf(fmaxf(v.z, 0.f)), f2bf(fmaxf(v.w, 0.f)));
  }
}

// ---- bucketing prep: hist + padded offsets + segtab, one block ----
__global__ void k_prep(const int* __restrict__ rel, int* __restrict__ po,
                       int* __restrict__ segtab, int* __restrict__ cur) {
  __shared__ int hist[NREL];
  __shared__ int tpo[NGRP + 1];   // tile-prefix offsets
  const int t = threadIdx.x;
  if (t < NREL) { hist[t] = 0; cur[t] = 0; }
  __syncthreads();
  for (int e = t; e < N_TOK; e += 256) atomicAdd(&hist[rel[e]], 1);
  __syncthreads();
  if (t == 0) {
    int acc = 0;
    for (int s = 0; s < NGRP; ++s) {
      int r = (s < NREL) ? s : s - NREL;
      tpo[s] = acc;
      acc += (hist[r] + 127) >> 7;
    }
    tpo[NGRP] = acc;
  }
  __syncthreads();
  if (t <= NGRP) po[t] = tpo[t] << 7;
  if (t < MAXT) {
    int s = -1;
    if (t < tpo[NGRP]) {           // largest s with tpo[s] <= t (skips empty segs)
      int lo = 0, hi = NGRP - 1;
      while (lo < hi) { int mid = (lo + hi + 1) >> 1; if (tpo[mid] <= t) lo = mid; else hi = mid - 1; }
      s = lo;
    }
    segtab[t] = s;
  }
}

__global__ void k_fill2(const int* __restrict__ rel, const int* __restrict__ dep,
                        const int* __restrict__ gov, const int* __restrict__ po,
                        int* __restrict__ cur, int* __restrict__ msrc,
                        int* __restrict__ mdst) {
  int e = blockIdx.x * blockDim.x + threadIdx.x;
  if (e < N_TOK) {
    int r = rel[e];
    int p = atomicAdd(&cur[r], 1);
    int pf = po[r] + p, pb = po[NREL + r] + p;
    msrc[pf] = gov[e]; mdst[pf] = dep[e];   // fwd: dep += W_r h[gov]
    msrc[pb] = dep[e]; mdst[pb] = gov[e];   // rev: gov += W_{R+r} h[dep]
  }
}

// ---- 128x128-tile bf16 MFMA GEMM ----
// KIND 0: FF — Cf[m0+row][col] = acc + bias  (plain store)
// KIND 2: merged self+edge — atomicAdd into zeroed Cf:
//   blockIdx.x <  STILE: self rows direct, W=Wself, bias=bself
//   blockIdx.x >= STILE: gather msrc / scatter mdst, W=Wrel[seg], bias=brel[seg]
template <int KIND>
__global__ __launch_bounds__(256) void k_mm(
    const u16* __restrict__ A,
    const u16* __restrict__ Wself, const u16* __restrict__ Wrel,
    const float* __restrict__ bself, const float* __restrict__ brel,
    const int* __restrict__ msrc, const int* __restrict__ mdst,
    const int* __restrict__ segtab,
    float* __restrict__ Cf, int Nn)
{
  bool isSelf = true;
  int me0 = 0;                         // edge row base in msrc/mdst
  const u16* Bsrc = Wself;
  const float* bb = bself;
  if (KIND == 2 && blockIdx.x >= STILE) {
    isSelf = false;
    const int et = blockIdx.x - STILE;
    const int seg = segtab[et];
    if (seg < 0) return;
    me0 = et * 128;
    Bsrc = Wrel + (size_t)seg * DIM * DIM;
    bb = brel + (size_t)seg * DIM;
  }
  const int m0 = blockIdx.x * 128;     // self/FF row base
  const int n0 = blockIdx.y * 128;

  __shared__ u16 As[128 * 64];   // 16 KB, 16B chunks XOR-swizzled by row&7
  __shared__ u16 Bs[128 * 64];

  const int t = threadIdx.x, w = t >> 6, l = t & 63;
  const int wm = (w >> 1) * 64, wn = (w & 1) * 64;
  const int lc = l & 15, h8 = l >> 4;
  const int wch = (t & 7) ^ ((t >> 3) & 7);   // swizzled write chunk

  const u16* gApt[4]; const u16* gBpt[4]; bool azero[4];
#pragma unroll
  for (int p = 0; p < 4; ++p) {
    const int row = p * 32 + (t >> 3);
    int arow;
    if (KIND == 2 && !isSelf) { arow = msrc[me0 + row]; azero[p] = (arow < 0); if (arow < 0) arow = 0; }
    else { arow = m0 + row; azero[p] = false; }
    gApt[p] = A + (size_t)arow * DIM + (t & 7) * 8;
    gBpt[p] = Bsrc + (size_t)(n0 + row) * DIM + (t & 7) * 8;
  }

  f32x4 acc[4][4] = {};

  for (int k0 = 0; k0 < DIM; k0 += 64) {
#pragma unroll
    for (int p = 0; p < 4; ++p) {
      const int row = p * 32 + (t >> 3);
      u16x8 av = {0, 0, 0, 0, 0, 0, 0, 0};
      if (!azero[p]) av = *reinterpret_cast<const u16x8*>(gApt[p] + k0);
      *reinterpret_cast<u16x8*>(&As[row * 64 + wch * 8]) = av;
      u16x8 bw = *reinterpret_cast<const u16x8*>(gBpt[p] + k0);
      *reinterpret_cast<u16x8*>(&Bs[row * 64 + wch * 8]) = bw;
    }
    __syncthreads();
#pragma unroll
    for (int ks = 0; ks < 2; ++ks) {
      const int rc = ks * 4 + h8;
      bf16x8 af[4], bfr[4];
#pragma unroll
      for (int mi = 0; mi < 4; ++mi)
        af[mi] = *reinterpret_cast<const bf16x8*>(&As[(wm + mi * 16 + lc) * 64 + (rc ^ (lc & 7)) * 8]);
#pragma unroll
      for (int ni = 0; ni < 4; ++ni)
        bfr[ni] = *reinterpret_cast<const bf16x8*>(&Bs[(wn + ni * 16 + lc) * 64 + (rc ^ (lc & 7)) * 8]);
#pragma unroll
      for (int mi = 0; mi < 4; ++mi)
#pragma unroll
        for (int ni = 0; ni < 4; ++ni)
          acc[mi][ni] = __builtin_amdgcn_mfma_f32_16x16x32_bf16(af[mi], bfr[ni], acc[mi][ni], 0, 0, 0);
    }
    __syncthreads();
  }

  // C/D layout (verified): col = lane&15, row = (lane>>4)*4 + reg
  float bv[4];
#pragma unroll
  for (int ni = 0; ni < 4; ++ni) bv[ni] = bb[n0 + wn + ni * 16 + lc];

#pragma unroll
  for (int mi = 0; mi < 4; ++mi)
#pragma unroll
    for (int j = 0; j < 4; ++j) {
      const int rloc = wm + mi * 16 + h8 * 4 + j;
      if (KIND == 2) {
        int dst;
        if (isSelf) dst = m0 + rloc;
        else { dst = mdst[me0 + rloc]; if (dst < 0) continue; }
        float* pout = Cf + (size_t)dst * DIM + n0 + wn + lc;
#pragma unroll
        for (int ni = 0; ni < 4; ++ni)
          unsafeAtomicAdd(pout + ni * 16, acc[mi][ni][j] + bv[ni]);
      } else {
        float* pout = Cf + (size_t)(m0 + rloc) * Nn + n0 + wn + lc;
#pragma unroll
        for (int ni = 0; ni < 4; ++ni)
          pout[ni * 16] = acc[mi][ni][j] + bv[ni];
      }
    }
}

extern "C" void kernel_launch(void* const* d_in, const int* in_sizes, int n_in,
                              void* d_out, int out_size, void* d_ws, size_t ws_size,
                              hipStream_t stream) {
  const float* x      = (const float*)d_in[0];
  const int*   dep    = (const int*)d_in[1];
  const int*   rel    = (const int*)d_in[2];
  const int*   gov    = (const int*)d_in[3];
  const float* W_self = (const float*)d_in[4];
  const float* b_self = (const float*)d_in[5];
  const float* W_rel  = (const float*)d_in[6];
  const float* b_rel  = (const float*)d_in[7];
  const float* W_ff   = (const float*)d_in[8];
  const float* b_ff   = (const float*)d_in[9];
  float* out = (float*)d_out;

  char* ws = (char*)d_ws;
  size_t o = 0;
  auto alloc = [&](size_t bytes) -> void* {
    void* p = ws + o;
    o = (o + bytes + 255) & ~(size_t)255;
    return p;
  };
  u16*   Wrel_bf  = (u16*)alloc((size_t)2 * NGRP * DIM * DIM * 2);
  u16*   Wself_bf = (u16*)alloc((size_t)2 * DIM * DIM * 2);
  u16*   Wff_bf   = (u16*)alloc((size_t)OUTD * DIM * 2);
  u16*   hb0      = (u16*)alloc((size_t)N_TOK * DIM * 2);
  u16*   hb1      = (u16*)alloc((size_t)N_TOK * DIM * 2);
  float* outf     = (float*)alloc((size_t)N_TOK * DIM * 4);
  int*   po       = (int*)alloc((NGRP + 1) * 4);
  int*   cur      = (int*)alloc(NREL * 4);
  int*   msrc     = (int*)alloc(MAXP * 4);   // MAXP*4 is 256-aligned ->
  int*   mdst     = (int*)alloc(MAXP * 4);   // msrc/mdst contiguous
  int*   segtab   = (int*)alloc(MAXT * 4);
  (void)ws_size; (void)in_sizes; (void)n_in; (void)out_size;

  // all fp32->bf16 conversions in one dispatch
  k_cvt4<<<2048, 256, 0, stream>>>(
      W_rel, Wrel_bf, 2 * NGRP * DIM * DIM / 4,
      W_self, Wself_bf, 2 * DIM * DIM / 4,
      W_ff, Wff_bf, OUTD * DIM / 4,
      x, hb0, N_TOK * DIM / 4);

  // message-list build: pad-poison (one memset covers contiguous msrc+mdst),
  // prep (hist+offsets+segtab+cur), fill
  hipMemsetAsync(msrc, 0xFF, (size_t)2 * MAXP * 4, stream);
  k_prep<<<1, 256, 0, stream>>>(rel, po, segtab, cur);
  k_fill2<<<N_TOK / 256, 256, 0, stream>>>(rel, dep, gov, po, cur, msrc, mdst);

  u16* hin = hb0;
  u16* hout = hb1;
  for (int l = 0; l < 2; ++l) {
    hipMemsetAsync(outf, 0, (size_t)N_TOK * DIM * 4, stream);
    // self + edge in ONE dispatch (928 blocks), all atomicAdd into outf
    k_mm<2><<<dim3(STILE + MAXT, DIM / 128), 256, 0, stream>>>(
        hin,
        Wself_bf + (size_t)l * DIM * DIM,
        Wrel_bf + (size_t)l * NGRP * DIM * DIM,
        b_self + (size_t)l * DIM,
        b_rel + (size_t)l * NGRP * DIM,
        msrc, mdst, segtab, outf, DIM);
    // h_{l+1} = bf16(relu(outf))
    k_cvtr<<<2048, 256, 0, stream>>>(outf, hout, N_TOK * DIM / 4);
    u16* tmp = hin; hin = hout; hout = tmp;
  }

  // final FF (plain store, fp32 out)
  k_mm<0><<<dim3(STILE, OUTD / 128), 256, 0, stream>>>(
      hin, Wff_bf, nullptr, b_ff, nullptr, nullptr, nullptr, nullptr, out, OUTD);
}

// Round 10
// 350.376 us; speedup vs baseline: 1.0599x; 1.0599x over previous
//
#include <hip/hip_runtime.h>

#define N_TOK 8192
#define DIM   512
#define NREL  20
#define NGRP  40          // 2R segments (0..19 fwd, 20..39 rev)
#define OUTD  256
#define STILE 64          // self m-tiles: 8192/128
#define MAXT  168         // max padded edge m-tiles (2 * (64+20) worst case)
#define MAXP  (MAXT*128)

typedef unsigned short u16;
typedef u16    u16x8  __attribute__((ext_vector_type(8)));
typedef __bf16 bf16x8 __attribute__((ext_vector_type(8)));
typedef float  f32x4  __attribute__((ext_vector_type(4)));

__device__ __forceinline__ u16 f2bf(float f) {
  union { float f; unsigned u; } v; v.f = f;
  return (u16)((v.u + 0x7FFFu + ((v.u >> 16) & 1u)) >> 16);  // RNE
}

// async global->LDS, 16B per lane; LDS dest = wave-uniform base + lane*16
__device__ __forceinline__ void gl16(const void* g, void* l) {
  __builtin_amdgcn_global_load_lds(
      (const __attribute__((address_space(1))) void*)g,
      (__attribute__((address_space(3))) void*)l, 16, 0, 0);
}

// ---- one dispatch: all fp32->bf16 conversions + zero outf0 ----
__global__ void k_cvt4(const float* __restrict__ s0, u16* __restrict__ d0, int m0,
                       const float* __restrict__ s1, u16* __restrict__ d1, int m1,
                       const float* __restrict__ s2, u16* __restrict__ d2, int m2,
                       const float* __restrict__ s3, u16* __restrict__ d3, int m3,
                       float4* __restrict__ z, int nz) {
  const int stride = gridDim.x * blockDim.x;
  const int t0 = blockIdx.x * blockDim.x + threadIdx.x;
#define CVT_LOOP(S, D, N)                                                    \
  for (int i = t0; i < N; i += stride) {                                     \
    float4 v = reinterpret_cast<const float4*>(S)[i];                        \
    reinterpret_cast<ushort4*>(D)[i] =                                       \
        make_ushort4(f2bf(v.x), f2bf(v.y), f2bf(v.z), f2bf(v.w));            \
  }
  CVT_LOOP(s0, d0, m0) CVT_LOOP(s1, d1, m1) CVT_LOOP(s2, d2, m2) CVT_LOOP(s3, d3, m3)
#undef CVT_LOOP
  const float4 zero = make_float4(0.f, 0.f, 0.f, 0.f);
  for (int i = t0; i < nz; i += stride) z[i] = zero;
}

// fp32 -> bf16 with ReLU; optionally zero another buffer (next layer's outf)
__global__ void k_cvtr(const float* __restrict__ in, u16* __restrict__ out,
                       float4* __restrict__ z, int n4) {
  const int stride = gridDim.x * blockDim.x;
  const int t0 = blockIdx.x * blockDim.x + threadIdx.x;
  for (int i = t0; i < n4; i += stride) {
    float4 v = reinterpret_cast<const float4*>(in)[i];
    reinterpret_cast<ushort4*>(out)[i] =
        make_ushort4(f2bf(fmaxf(v.x, 0.f)), f2bf(fmaxf(v.y, 0.f)),
                     f2bf(fmaxf(v.z, 0.f)), f2bf(fmaxf(v.w, 0.f)));
  }
  if (z != nullptr) {
    const float4 zero = make_float4(0.f, 0.f, 0.f, 0.f);
    for (int i = t0; i < n4; i += stride) z[i] = zero;
  }
}

// ---- prep: hist + padded offsets + segtab + pad poison (one block) ----
__global__ void k_prep(const int* __restrict__ rel, int* __restrict__ po,
                       int* __restrict__ segtab, int* __restrict__ cur,
                       int* __restrict__ msrc, int* __restrict__ mdst) {
  __shared__ int hist[NREL];
  __shared__ int tpo[NGRP + 1];   // tile-prefix offsets
  const int t = threadIdx.x;
  if (t < NREL) { hist[t] = 0; cur[t] = 0; }
  __syncthreads();
  for (int e = t; e < N_TOK; e += 256) atomicAdd(&hist[rel[e]], 1);
  __syncthreads();
  if (t == 0) {
    int acc = 0;
    for (int s = 0; s < NGRP; ++s) {
      int r = (s < NREL) ? s : s - NREL;
      tpo[s] = acc;
      acc += (hist[r] + 127) >> 7;
    }
    tpo[NGRP] = acc;
  }
  __syncthreads();
  if (t <= NGRP) po[t] = tpo[t] << 7;
  if (t < MAXT) {
    int s = -1;
    if (t < tpo[NGRP]) {
      s = 0;
      for (int q = 1; q < NGRP; ++q) if (tpo[q] <= t) s = q;
    }
    segtab[t] = s;
  }
  __syncthreads();
  // pad rows: msrc=0 (safe gather, output discarded), mdst=-1 (no scatter)
  for (int s = 0; s < NGRP; ++s) {
    const int r = (s < NREL) ? s : s - NREL;
    const int start = (tpo[s] << 7) + hist[r];
    const int end   = tpo[s + 1] << 7;
    for (int i = start + t; i < end; i += 256) { msrc[i] = 0; mdst[i] = -1; }
  }
}

__global__ void k_fill2(const int* __restrict__ rel, const int* __restrict__ dep,
                        const int* __restrict__ gov, const int* __restrict__ po,
                        int* __restrict__ cur, int* __restrict__ msrc,
                        int* __restrict__ mdst) {
  int e = blockIdx.x * blockDim.x + threadIdx.x;
  if (e < N_TOK) {
    int r = rel[e];
    int p = atomicAdd(&cur[r], 1);
    int pf = po[r] + p, pb = po[NREL + r] + p;
    msrc[pf] = gov[e]; mdst[pf] = dep[e];   // fwd: dep += W_r h[gov]
    msrc[pb] = dep[e]; mdst[pb] = gov[e];   // rev: gov += W_{R+r} h[dep]
  }
}

// ---- 128x128-tile bf16 MFMA GEMM, global_load_lds staging ----
// KIND 0: FF — Cf[m0+row][col] = acc + bias  (plain store)
// KIND 2: merged self+edge — atomicAdd into zeroed Cf
template <int KIND>
__global__ __launch_bounds__(256) void k_mm(
    const u16* __restrict__ A,
    const u16* __restrict__ Wself, const u16* __restrict__ Wrel,
    const float* __restrict__ bself, const float* __restrict__ brel,
    const int* __restrict__ msrc, const int* __restrict__ mdst,
    const int* __restrict__ segtab,
    float* __restrict__ Cf, int Nn)
{
  bool isSelf = true;
  int me0 = 0;
  const u16* Bsrc = Wself;
  const float* bb = bself;
  if (KIND == 2 && blockIdx.x >= STILE) {
    isSelf = false;
    const int et = blockIdx.x - STILE;
    const int seg = segtab[et];
    if (seg < 0) return;
    me0 = et * 128;
    Bsrc = Wrel + (size_t)seg * DIM * DIM;
    bb = brel + (size_t)seg * DIM;
  }
  const int m0 = blockIdx.x * 128;
  const int n0 = blockIdx.y * 128;

  __shared__ u16 As[128 * 64];   // 16 KB; slot-chunk c of row r holds global chunk c^(r&7)
  __shared__ u16 Bs[128 * 64];

  const int t = threadIdx.x, w = t >> 6, l = t & 63;
  const int wm = (w >> 1) * 64, wn = (w & 1) * 64;
  const int lc = l & 15, h8 = l >> 4;
  // pre-swizzled SOURCE chunk: linear lane->LDS placement then yields the
  // same XOR layout the read side expects (both-sides involution, rule #21)
  const int chunk = (t & 7) ^ ((t >> 3) & 7);

  const u16* gApt[4]; const u16* gBpt[4];
#pragma unroll
  for (int p = 0; p < 4; ++p) {
    const int row = p * 32 + (t >> 3);
    int arow;
    if (KIND == 2 && !isSelf) arow = msrc[me0 + row];   // pads preset to 0
    else arow = m0 + row;
    gApt[p] = A + (size_t)arow * DIM + chunk * 8;
    gBpt[p] = Bsrc + (size_t)(n0 + row) * DIM + chunk * 8;
  }

  f32x4 acc[4][4] = {};

  for (int k0 = 0; k0 < DIM; k0 += 64) {
#pragma unroll
    for (int p = 0; p < 4; ++p) {
      // wave-uniform LDS byte offset: rows p*32+w*8 .. +8 (1 KB per wave-call)
      const unsigned lofs =
          (unsigned)__builtin_amdgcn_readfirstlane((p * 32 + w * 8) * 128);
      gl16(gApt[p] + k0, (char*)As + lofs);
      gl16(gBpt[p] + k0, (char*)Bs + lofs);
    }
    __syncthreads();   // drains vmcnt -> tiles resident
#pragma unroll
    for (int ks = 0; ks < 2; ++ks) {
      const int rc = ks * 4 + h8;
      bf16x8 af[4], bfr[4];
#pragma unroll
      for (int mi = 0; mi < 4; ++mi)
        af[mi] = *reinterpret_cast<const bf16x8*>(&As[(wm + mi * 16 + lc) * 64 + (rc ^ (lc & 7)) * 8]);
#pragma unroll
      for (int ni = 0; ni < 4; ++ni)
        bfr[ni] = *reinterpret_cast<const bf16x8*>(&Bs[(wn + ni * 16 + lc) * 64 + (rc ^ (lc & 7)) * 8]);
#pragma unroll
      for (int mi = 0; mi < 4; ++mi)
#pragma unroll
        for (int ni = 0; ni < 4; ++ni)
          acc[mi][ni] = __builtin_amdgcn_mfma_f32_16x16x32_bf16(af[mi], bfr[ni], acc[mi][ni], 0, 0, 0);
    }
    __syncthreads();   // all reads done before next-step overwrite
  }

  // C/D layout (verified): col = lane&15, row = (lane>>4)*4 + reg
  float bv[4];
#pragma unroll
  for (int ni = 0; ni < 4; ++ni) bv[ni] = bb[n0 + wn + ni * 16 + lc];

#pragma unroll
  for (int mi = 0; mi < 4; ++mi)
#pragma unroll
    for (int j = 0; j < 4; ++j) {
      const int rloc = wm + mi * 16 + h8 * 4 + j;
      if (KIND == 2) {
        int dst;
        if (isSelf) dst = m0 + rloc;
        else { dst = mdst[me0 + rloc]; if (dst < 0) continue; }
        float* pout = Cf + (size_t)dst * DIM + n0 + wn + lc;
#pragma unroll
        for (int ni = 0; ni < 4; ++ni)
          unsafeAtomicAdd(pout + ni * 16, acc[mi][ni][j] + bv[ni]);
      } else {
        float* pout = Cf + (size_t)(m0 + rloc) * Nn + n0 + wn + lc;
#pragma unroll
        for (int ni = 0; ni < 4; ++ni)
          pout[ni * 16] = acc[mi][ni][j] + bv[ni];
      }
    }
}

extern "C" void kernel_launch(void* const* d_in, const int* in_sizes, int n_in,
                              void* d_out, int out_size, void* d_ws, size_t ws_size,
                              hipStream_t stream) {
  const float* x      = (const float*)d_in[0];
  const int*   dep    = (const int*)d_in[1];
  const int*   rel    = (const int*)d_in[2];
  const int*   gov    = (const int*)d_in[3];
  const float* W_self = (const float*)d_in[4];
  const float* b_self = (const float*)d_in[5];
  const float* W_rel  = (const float*)d_in[6];
  const float* b_rel  = (const float*)d_in[7];
  const float* W_ff   = (const float*)d_in[8];
  const float* b_ff   = (const float*)d_in[9];
  float* out = (float*)d_out;

  char* ws = (char*)d_ws;
  size_t o = 0;
  auto alloc = [&](size_t bytes) -> void* {
    void* p = ws + o;
    o = (o + bytes + 255) & ~(size_t)255;
    return p;
  };
  u16*   Wrel_bf  = (u16*)alloc((size_t)2 * NGRP * DIM * DIM * 2);
  u16*   Wself_bf = (u16*)alloc((size_t)2 * DIM * DIM * 2);
  u16*   Wff_bf   = (u16*)alloc((size_t)OUTD * DIM * 2);
  u16*   hb0      = (u16*)alloc((size_t)N_TOK * DIM * 2);
  u16*   hb1      = (u16*)alloc((size_t)N_TOK * DIM * 2);
  float* outf0    = (float*)alloc((size_t)N_TOK * DIM * 4);
  float* outf1    = (float*)alloc((size_t)N_TOK * DIM * 4);
  int*   po       = (int*)alloc((NGRP + 1) * 4);
  int*   cur      = (int*)alloc(NREL * 4);
  int*   msrc     = (int*)alloc(MAXP * 4);
  int*   mdst     = (int*)alloc(MAXP * 4);
  int*   segtab   = (int*)alloc(MAXT * 4);
  (void)ws_size; (void)in_sizes; (void)n_in; (void)out_size;

  // 1: all conversions + zero outf0
  k_cvt4<<<2048, 256, 0, stream>>>(
      W_rel, Wrel_bf, 2 * NGRP * DIM * DIM / 4,
      W_self, Wself_bf, 2 * DIM * DIM / 4,
      W_ff, Wff_bf, OUTD * DIM / 4,
      x, hb0, N_TOK * DIM / 4,
      (float4*)outf0, N_TOK * DIM / 4);
  // 2: hist + offsets + segtab + pad poison
  k_prep<<<1, 256, 0, stream>>>(rel, po, segtab, cur, msrc, mdst);
  // 3: scatter real message entries
  k_fill2<<<N_TOK / 256, 256, 0, stream>>>(rel, dep, gov, po, cur, msrc, mdst);

  // 4: layer 0 self+edge (atomic into outf0)
  k_mm<2><<<dim3(STILE + MAXT, DIM / 128), 256, 0, stream>>>(
      hb0, Wself_bf, Wrel_bf, b_self, b_rel, msrc, mdst, segtab, outf0, DIM);
  // 5: h1 = bf16(relu(outf0)); zero outf1
  k_cvtr<<<2048, 256, 0, stream>>>(outf0, hb1, (float4*)outf1, N_TOK * DIM / 4);
  // 6: layer 1
  k_mm<2><<<dim3(STILE + MAXT, DIM / 128), 256, 0, stream>>>(
      hb1, Wself_bf + (size_t)DIM * DIM, Wrel_bf + (size_t)NGRP * DIM * DIM,
      b_self + DIM, b_rel + (size_t)NGRP * DIM, msrc, mdst, segtab, outf1, DIM);
  // 7: h2 = bf16(relu(outf1))
  k_cvtr<<<2048, 256, 0, stream>>>(outf1, hb0, nullptr, N_TOK * DIM / 4);
  // 8: final FF (plain store, fp32 out)
  k_mm<0><<<dim3(STILE, OUTD / 128), 256, 0, stream>>>(
      hb0, Wff_bf, nullptr, b_ff, nullptr, nullptr, nullptr, nullptr, out, OUTD);
}